// Round 2
// baseline (266.458 us; speedup 1.0000x reference)
//
#include <hip/hip_runtime.h>
#include <hip/hip_bf16.h>

#define TEMP_INV 10.0f
#define RPB 8   // rows per block

typedef float vf4 __attribute__((ext_vector_type(4)));

// Grid: B/RPB blocks of 256 threads. Each block computes softmax bins for RPB
// rows, factorizes the 4^7 outer product as prodHi[64]*prodMid[64]*v6[4],
// and streams out RPB * 64 KiB with nontemporal float4 stores.
__global__ __launch_bounds__(256) void dtree_kernel(
    const float* __restrict__ x,        // (B, 7)
    const float* __restrict__ cut,      // (7, 3)
    float* __restrict__ out,            // (B, 16384)
    int B)
{
    const int t  = threadIdx.x;
    const int r0 = blockIdx.x * RPB;

    __shared__ float sb[RPB][7][4];     // per-row, per-feature softmax bins
    __shared__ float prodHi[RPB][64];   // features 0..2
    __shared__ float prodMid[RPB][64];  // features 3..5

    // ---- setup: 56 threads, one per (row, feature) ----
    if (t < RPB * 7) {
        const int r = t / 7;            // local row
        const int f = t - r * 7;        // feature
        const int row = r0 + r;

        float c0 = cut[f * 3 + 0];
        float c1 = cut[f * 3 + 1];
        float c2 = cut[f * 3 + 2];
        float lo = fminf(c0, c1), hi = fmaxf(c0, c1);
        float m0 = fminf(lo, c2);
        float m2 = fmaxf(hi, c2);
        float m1 = (c0 + c1 + c2) - m0 - m2;

        float xb = (row < B) ? x[(size_t)row * 7 + f] : 0.0f;
        float h0 = xb;
        float h1 = xb * 2.0f - m0;
        float h2 = xb * 3.0f - (m0 + m1);
        float h3 = xb * 4.0f - (m0 + m1 + m2);
        h0 *= TEMP_INV; h1 *= TEMP_INV; h2 *= TEMP_INV; h3 *= TEMP_INV;
        float mx = fmaxf(fmaxf(h0, h1), fmaxf(h2, h3));
        float e0 = __expf(h0 - mx);
        float e1 = __expf(h1 - mx);
        float e2 = __expf(h2 - mx);
        float e3 = __expf(h3 - mx);
        float inv = 1.0f / (e0 + e1 + e2 + e3);
        sb[r][f][0] = e0 * inv;
        sb[r][f][1] = e1 * inv;
        sb[r][f][2] = e2 * inv;
        sb[r][f][3] = e3 * inv;
    }
    __syncthreads();

    // ---- factor products: RPB*64 entries each for Hi and Mid ----
    for (int e = t; e < RPB * 64; e += 256) {
        int r = e >> 6;
        int k = e & 63;
        prodHi[r][k]  = sb[r][0][(k >> 4) & 3] * sb[r][1][(k >> 2) & 3] * sb[r][2][k & 3];
        prodMid[r][k] = sb[r][3][(k >> 4) & 3] * sb[r][4][(k >> 2) & 3] * sb[r][5][k & 3];
    }
    __syncthreads();

    // ---- streaming store: RPB rows x 4096 float4 per row ----
    const float pmidSel = 0.0f; (void)pmidSel;
#pragma unroll
    for (int rr = 0; rr < RPB; ++rr) {
        const int row = r0 + rr;
        if (row >= B) break;
        const float v60 = sb[rr][6][0];
        const float v61 = sb[rr][6][1];
        const float v62 = sb[rr][6][2];
        const float v63 = sb[rr][6][3];
        const float pmid = prodMid[rr][t & 63];       // loop-invariant per row
        vf4* __restrict__ o = (vf4*)(out + (size_t)row * 16384);
#pragma unroll
        for (int j = 0; j < 16; ++j) {
            const int n = j * 256 + t;                // float4 index in row
            const float P = prodHi[rr][n >> 6] * pmid; // wave-uniform LDS read
            vf4 v;
            v.x = P * v60; v.y = P * v61; v.z = P * v62; v.w = P * v63;
            __builtin_nontemporal_store(v, &o[n]);
        }
    }
}

extern "C" void kernel_launch(void* const* d_in, const int* in_sizes, int n_in,
                              void* d_out, int out_size, void* d_ws, size_t ws_size,
                              hipStream_t stream) {
    const float* x   = (const float*)d_in[0];
    const float* cut = (const float*)d_in[1];
    float* out = (float*)d_out;
    const int B = in_sizes[0] / 7;                    // 4096
    const int grid = (B + RPB - 1) / RPB;             // 512
    dtree_kernel<<<grid, 256, 0, stream>>>(x, cut, out, B);
}

// Round 3
// 255.189 us; speedup vs baseline: 1.0442x; 1.0442x over previous
//
#include <hip/hip_runtime.h>
#include <hip/hip_bf16.h>

#define TEMP_INV 10.0f
#define RPB 2   // rows per block -> grid 2048 = exactly one resident generation

typedef float vf4 __attribute__((ext_vector_type(4)));

// Grid: B/RPB = 2048 blocks x 256 threads = 8192 waves = 32 waves/CU x 256 CU:
// the whole grid is co-resident, no scheduling generations, no tail.
// __launch_bounds__(256, 8): 8 waves/EU -> VGPR cap 64 so occupancy holds.
__global__ __launch_bounds__(256, 8) void dtree_kernel(
    const float* __restrict__ x,        // (B, 7)
    const float* __restrict__ cut,      // (7, 3)
    float* __restrict__ out,            // (B, 16384)
    int B)
{
    const int t  = threadIdx.x;
    const int r0 = blockIdx.x * RPB;

    __shared__ float sb[RPB][7][4];     // per-row, per-feature softmax bins
    __shared__ float prodHi[RPB][64];   // features 0..2
    __shared__ float prodMid[RPB][64];  // features 3..5

    // ---- setup: one thread per (row, feature) ----
    if (t < RPB * 7) {
        const int r = t / 7;
        const int f = t - r * 7;
        const int row = r0 + r;

        float c0 = cut[f * 3 + 0];
        float c1 = cut[f * 3 + 1];
        float c2 = cut[f * 3 + 2];
        float lo = fminf(c0, c1), hi = fmaxf(c0, c1);
        float m0 = fminf(lo, c2);
        float m2 = fmaxf(hi, c2);
        float m1 = (c0 + c1 + c2) - m0 - m2;

        float xb = (row < B) ? x[(size_t)row * 7 + f] : 0.0f;
        float h0 = xb;
        float h1 = xb * 2.0f - m0;
        float h2 = xb * 3.0f - (m0 + m1);
        float h3 = xb * 4.0f - (m0 + m1 + m2);
        h0 *= TEMP_INV; h1 *= TEMP_INV; h2 *= TEMP_INV; h3 *= TEMP_INV;
        float mx = fmaxf(fmaxf(h0, h1), fmaxf(h2, h3));
        float e0 = __expf(h0 - mx);
        float e1 = __expf(h1 - mx);
        float e2 = __expf(h2 - mx);
        float e3 = __expf(h3 - mx);
        float inv = 1.0f / (e0 + e1 + e2 + e3);
        sb[r][f][0] = e0 * inv;
        sb[r][f][1] = e1 * inv;
        sb[r][f][2] = e2 * inv;
        sb[r][f][3] = e3 * inv;
    }
    __syncthreads();

    // ---- factor products: RPB*64 = 128 entries ----
    if (t < RPB * 64) {
        const int r = t >> 6;
        const int k = t & 63;
        prodHi[r][k]  = sb[r][0][(k >> 4) & 3] * sb[r][1][(k >> 2) & 3] * sb[r][2][k & 3];
        prodMid[r][k] = sb[r][3][(k >> 4) & 3] * sb[r][4][(k >> 2) & 3] * sb[r][5][k & 3];
    }
    __syncthreads();

    const int w = t >> 6;               // wave id within block, 0..3

#pragma unroll
    for (int rr = 0; rr < RPB; ++rr) {
        const int row = r0 + rr;
        if (row >= B) break;
        const float v60 = sb[rr][6][0];
        const float v61 = sb[rr][6][1];
        const float v62 = sb[rr][6][2];
        const float v63 = sb[rr][6][3];
        const float pmid = prodMid[rr][t & 63];

        // Preload all LDS-dependent values into registers: the store loop
        // below then has NO lgkmcnt waits — pure back-to-back dwordx4 stores.
        float P[16];
#pragma unroll
        for (int j = 0; j < 16; ++j)
            P[j] = prodHi[rr][j * 4 + w] * pmid;   // wave-uniform LDS reads

        vf4* __restrict__ o = (vf4*)(out + (size_t)row * 16384);
#pragma unroll
        for (int j = 0; j < 16; ++j) {
            vf4 v;
            v.x = P[j] * v60; v.y = P[j] * v61; v.z = P[j] * v62; v.w = P[j] * v63;
            o[j * 256 + t] = v;
        }
    }
}

extern "C" void kernel_launch(void* const* d_in, const int* in_sizes, int n_in,
                              void* d_out, int out_size, void* d_ws, size_t ws_size,
                              hipStream_t stream) {
    const float* x   = (const float*)d_in[0];
    const float* cut = (const float*)d_in[1];
    float* out = (float*)d_out;
    const int B = in_sizes[0] / 7;                    // 4096
    const int grid = (B + RPB - 1) / RPB;             // 2048
    dtree_kernel<<<grid, 256, 0, stream>>>(x, cut, out, B);
}

// Round 4
// 252.883 us; speedup vs baseline: 1.0537x; 1.0091x over previous
//
#include <hip/hip_runtime.h>
#include <hip/hip_bf16.h>

#define TEMP_INV 10.0f
#define RPB 8   // rows per block -> grid 512 = 2 blocks/CU, 8 waves/CU

typedef float vf4 __attribute__((ext_vector_type(4)));

// Fill-mimicking structure: few waves/CU, each wave streams CONTIGUOUS 16 KiB
// per row (quarter-row chunk), back-to-back dwordx4 stores with no LDS reads
// in the loop. out[row] factorized as prodHi[64]*prodMid[64]*v6[4].
__global__ __launch_bounds__(256) void dtree_kernel(
    const float* __restrict__ x,        // (B, 7)
    const float* __restrict__ cut,      // (7, 3)
    float* __restrict__ out,            // (B, 16384)
    int B)
{
    const int t    = threadIdx.x;
    const int w    = t >> 6;            // wave 0..3
    const int lane = t & 63;
    const int r0   = blockIdx.x * RPB;

    __shared__ float sb[RPB][7][4];
    __shared__ float prodHi[RPB][64];   // features 0..2
    __shared__ float prodMid[RPB][64];  // features 3..5

    // ---- setup: one thread per (row, feature) ----
    if (t < RPB * 7) {
        const int r = t / 7;
        const int f = t - r * 7;
        const int row = r0 + r;

        float c0 = cut[f * 3 + 0];
        float c1 = cut[f * 3 + 1];
        float c2 = cut[f * 3 + 2];
        float lo = fminf(c0, c1), hi = fmaxf(c0, c1);
        float m0 = fminf(lo, c2);
        float m2 = fmaxf(hi, c2);
        float m1 = (c0 + c1 + c2) - m0 - m2;

        float xb = (row < B) ? x[(size_t)row * 7 + f] : 0.0f;
        float h0 = xb;
        float h1 = xb * 2.0f - m0;
        float h2 = xb * 3.0f - (m0 + m1);
        float h3 = xb * 4.0f - (m0 + m1 + m2);
        h0 *= TEMP_INV; h1 *= TEMP_INV; h2 *= TEMP_INV; h3 *= TEMP_INV;
        float mx = fmaxf(fmaxf(h0, h1), fmaxf(h2, h3));
        float e0 = __expf(h0 - mx);
        float e1 = __expf(h1 - mx);
        float e2 = __expf(h2 - mx);
        float e3 = __expf(h3 - mx);
        float inv = 1.0f / (e0 + e1 + e2 + e3);
        sb[r][f][0] = e0 * inv;
        sb[r][f][1] = e1 * inv;
        sb[r][f][2] = e2 * inv;
        sb[r][f][3] = e3 * inv;
    }
    __syncthreads();

    // ---- factor tables: RPB*64 = 512 entries, one per thread x2 ----
    for (int e = t; e < RPB * 64; e += 256) {
        const int r = e >> 6;
        const int k = e & 63;
        prodHi[r][k]  = sb[r][0][(k >> 4) & 3] * sb[r][1][(k >> 2) & 3] * sb[r][2][k & 3];
        prodMid[r][k] = sb[r][3][(k >> 4) & 3] * sb[r][4][(k >> 2) & 3] * sb[r][5][k & 3];
    }
    __syncthreads();

    // ---- streaming stores: each wave owns a contiguous quarter-row ----
#pragma unroll 1
    for (int rr = 0; rr < RPB; ++rr) {
        const int row = r0 + rr;
        if (row >= B) break;
        const float v60 = sb[rr][6][0];
        const float v61 = sb[rr][6][1];
        const float v62 = sb[rr][6][2];
        const float v63 = sb[rr][6][3];
        const float pmid = prodMid[rr][lane];

        // Quarter-row chunk: float4 indices [w*1024, w*1024+1024).
        // j-th store: n4 = w*1024 + j*64 + lane  ->  prodHi idx = w*16 + j.
        float P[16];
#pragma unroll
        for (int j = 0; j < 16; ++j)
            P[j] = prodHi[rr][w * 16 + j] * pmid;   // wave-uniform LDS reads

        vf4* __restrict__ o = (vf4*)(out + (size_t)row * 16384) + (w * 1024 + lane);
#pragma unroll
        for (int j = 0; j < 16; ++j) {
            vf4 v;
            v.x = P[j] * v60; v.y = P[j] * v61; v.z = P[j] * v62; v.w = P[j] * v63;
            o[j * 64] = v;                          // contiguous 1 KiB per wave-store
        }
    }
}

extern "C" void kernel_launch(void* const* d_in, const int* in_sizes, int n_in,
                              void* d_out, int out_size, void* d_ws, size_t ws_size,
                              hipStream_t stream) {
    const float* x   = (const float*)d_in[0];
    const float* cut = (const float*)d_in[1];
    float* out = (float*)d_out;
    const int B = in_sizes[0] / 7;                    // 4096
    const int grid = (B + RPB - 1) / RPB;             // 512
    dtree_kernel<<<grid, 256, 0, stream>>>(x, cut, out, B);
}